// Round 3
// baseline (452.208 us; speedup 1.0000x reference)
//
#include <hip/hip_runtime.h>
#include <cstdint>
#include <cstddef>

// Problem dims (B, D, F, T, H) = (256, 128, 8, 128, 128)
#define Bn 256
#define Dn 128
#define Fn 8
#define Tn 128
#define Hn 128
#define Kn 1024   // D*F
#define Mn 512    // 4*H

typedef float f32x4 __attribute__((ext_vector_type(4)));
typedef short s16x8 __attribute__((ext_vector_type(8)));
typedef _Float16 h16x2 __attribute__((ext_vector_type(2)));
typedef _Float16 h16x8 __attribute__((ext_vector_type(8)));

#if defined(__has_builtin)
#if __has_builtin(__builtin_amdgcn_fdot2)
#define HAVE_FDOT2 1
#else
#define HAVE_FDOT2 0
#endif
#if __has_builtin(__builtin_amdgcn_cvt_pk_bf16_f32)
#define HAVE_PK_BF16 1
#else
#define HAVE_PK_BF16 0
#endif
#else
#define HAVE_FDOT2 0
#define HAVE_PK_BF16 0
#endif

__device__ __forceinline__ unsigned short f32_to_bf16_rne(float f) {
  union { float f; uint32_t u; } v; v.f = f;
  uint32_t u = v.u;
  u += 0x7fffu + ((u >> 16) & 1u);
  return (unsigned short)(u >> 16);
}
__device__ __forceinline__ uint32_t pack2_bf16(float a, float b) {
#if HAVE_PK_BF16
  typedef __bf16 bf16x2_t __attribute__((ext_vector_type(2)));
  union { bf16x2_t v; uint32_t u; } cv;
  cv.v = __builtin_amdgcn_cvt_pk_bf16_f32(a, b);
  return cv.u;
#else
  return (uint32_t)f32_to_bf16_rne(a) | ((uint32_t)f32_to_bf16_rne(b) << 16);
#endif
}
__device__ __forceinline__ float sigm(float x) { return 1.0f / (1.0f + __expf(-x)); }
__device__ __forceinline__ float tanh_fast(float x) { return 1.0f - 2.0f / (__expf(2.0f * x) + 1.0f); }

// ---------------------------------------------------------------------------
// K1: ex[b,d] = input[b,d,:,:] . w_x   (one wave per (b,d))
// softmax shift-invariance kills the h/c/b_attn term entirely.
// ---------------------------------------------------------------------------
__global__ __launch_bounds__(256) void k_ex(const float* __restrict__ input,
                                            const float* __restrict__ w_attn,
                                            float* __restrict__ ex) {
  __shared__ float wx[Kn];
  const int tid = threadIdx.x;
  ((float4*)wx)[tid] = ((const float4*)(w_attn + 2 * Hn))[tid];
  __syncthreads();
  const int w = tid >> 6, lane = tid & 63;
  const int gid = blockIdx.x * 4 + w;  // b*128 + d
  const float4* xp = (const float4*)(input + (size_t)gid * Kn);
  const float4* wx4 = (const float4*)wx;
  float acc = 0.f;
#pragma unroll
  for (int r = 0; r < 4; ++r) {
    float4 x = xp[lane + r * 64];
    float4 ww = wx4[lane + r * 64];
    acc += x.x * ww.x + x.y * ww.y + x.z * ww.z + x.w * ww.w;
  }
#pragma unroll
  for (int off = 32; off; off >>= 1) acc += __shfl_xor(acc, off);
  if (lane == 0) ex[gid] = acc;
}

// ---------------------------------------------------------------------------
// K2 (merged prep):
//  blocks 0..255 : W_ih -> hi/lo bf16 MFMA A-frags
//  blocks 256..383: W_hh -> packed f16 pairs transposed (whhp[kk*512+j])
// ---------------------------------------------------------------------------
__global__ __launch_bounds__(256) void k_prep(const float* __restrict__ W_ih,
                                              const float* __restrict__ W_hh,
                                              unsigned short* __restrict__ whi,
                                              unsigned short* __restrict__ wlo,
                                              uint32_t* __restrict__ whhp) {
  const int bid = blockIdx.x;
  const int tid = threadIdx.x;
  if (bid < 256) {
    const int gid = bid * 256 + tid;  // 65536 groups of 8
    const int lane = gid & 63;
    const int kt = (gid >> 6) & 31;
    const int mt = gid >> 11;
    const int row = mt * 16 + (lane & 15);
    const int col = kt * 32 + (lane >> 4) * 8;
    const float* src = W_ih + row * Kn + col;
    unsigned short hi8[8], lo8[8];
#pragma unroll
    for (int j = 0; j < 8; ++j) {
      float wv = src[j];
      unsigned short h = f32_to_bf16_rne(wv);
      hi8[j] = h;
      union { uint32_t u; float f; } hb; hb.u = ((uint32_t)h) << 16;
      lo8[j] = f32_to_bf16_rne(wv - hb.f);
    }
    uint4 ph, pl;
    ph.x = (uint32_t)hi8[0] | ((uint32_t)hi8[1] << 16);
    ph.y = (uint32_t)hi8[2] | ((uint32_t)hi8[3] << 16);
    ph.z = (uint32_t)hi8[4] | ((uint32_t)hi8[5] << 16);
    ph.w = (uint32_t)hi8[6] | ((uint32_t)hi8[7] << 16);
    pl.x = (uint32_t)lo8[0] | ((uint32_t)lo8[1] << 16);
    pl.y = (uint32_t)lo8[2] | ((uint32_t)lo8[3] << 16);
    pl.z = (uint32_t)lo8[4] | ((uint32_t)lo8[5] << 16);
    pl.w = (uint32_t)lo8[6] | ((uint32_t)lo8[7] << 16);
    ((uint4*)whi)[gid] = ph;
    ((uint4*)wlo)[gid] = pl;
  } else {
    const int g = (bid - 256) * 256 + tid;  // 32768
    const int j = g & 511, kk = g >> 9;
    float2 wv = ((const float2*)(W_hh + (size_t)j * Hn))[kk];
    h16x2 t2; t2.x = (_Float16)wv.x; t2.y = (_Float16)wv.y;
    union { h16x2 h; uint32_t u; } cv; cv.h = t2;
    whhp[kk * 512 + j] = cv.u;
  }
}

// ---------------------------------------------------------------------------
// K3: gates GEMM. grid = 1024: b = (bid&7)|((bid>>5)<<3), p = (bid>>3)&3 so
// the 4 panels of one b share an XCD (bids differ by 8/16/24) and co-reside
// -> input[b] fetched ~once per XCD. 256 thr. Conflict-free staging layout
// [kb][t][8k] with lane-contiguous ds_write_b128. Register double-buffer for
// W frags + x prefetch; one barrier per K-tile.
// ---------------------------------------------------------------------------
__global__ __launch_bounds__(256, 2) void k_gates(
    const float* __restrict__ input, const float* __restrict__ ex,
    const unsigned short* __restrict__ whi, const unsigned short* __restrict__ wlo,
    unsigned short* __restrict__ gx) {
  __shared__ __align__(16) unsigned char smem[34816];
  __shared__ float a_lds[Dn];
  __shared__ float sred[8];
  unsigned short* buf0 = (unsigned short*)smem;
  unsigned short* buf1 = buf0 + 8192;
  _Float16* lds_out = (_Float16*)smem;

  const int tid = threadIdx.x;
  const int bid = blockIdx.x;
  const int p = (bid >> 3) & 3;
  const int b = (bid & 7) | ((bid >> 5) << 3);
  const int w = tid >> 6;
  const int lane = tid & 63;
  const int quad = lane >> 4;
  const int l15 = lane & 15;

  // ---- in-block softmax over ex[b,:] -> a_lds ----
  float v = (tid < Dn) ? ex[b * Dn + tid] : -3.4e38f;
  float m = v;
#pragma unroll
  for (int off = 32; off; off >>= 1) m = fmaxf(m, __shfl_xor(m, off));
  if (lane == 0) sred[w] = m;
  __syncthreads();
  m = fmaxf(fmaxf(sred[0], sred[1]), fmaxf(sred[2], sred[3]));
  float e = (tid < Dn) ? __expf(v - m) : 0.f;
  float s = e;
#pragma unroll
  for (int off = 32; off; off >>= 1) s += __shfl_xor(s, off);
  if (lane == 0) sred[4 + w] = s;
  __syncthreads();
  s = sred[4] + sred[5] + sred[6] + sred[7];
  if (tid < Dn) a_lds[tid] = e / s;

  f32x4 acc[2][8];
#pragma unroll
  for (int i = 0; i < 2; ++i)
#pragma unroll
    for (int j = 0; j < 8; ++j) { f32x4 z = {0.f, 0.f, 0.f, 0.f}; acc[i][j] = z; }

  const float* xb = input + (size_t)b * Kn * Tn;
  const int mtg0 = p * 8 + w * 2;

  // W fragment register double-buffer: idx = mt*4 + kf*2 + (0=hi,1=lo)
  s16x8 wcur[8], wnxt[8];
#pragma unroll
  for (int mt = 0; mt < 2; ++mt)
#pragma unroll
    for (int kf = 0; kf < 2; ++kf) {
      const size_t fo = (((size_t)(mtg0 + mt) * 32 + kf) * 64 + lane) * 8;
      wcur[mt * 4 + kf * 2 + 0] = *(const s16x8*)(whi + fo);
      wcur[mt * 4 + kf * 2 + 1] = *(const s16x8*)(wlo + fo);
    }

  __syncthreads();  // a_lds ready

  // ---- stage tile 0 ----
  float xr[2][2][8];
#pragma unroll
  for (int ck = 0; ck < 2; ++ck)
#pragma unroll
    for (int ct = 0; ct < 2; ++ct) {
      const int kb = 2 * w + ck;
      const float* col = xb + (size_t)(kb * 8) * Tn + lane + 64 * ct;
#pragma unroll
      for (int j = 0; j < 8; ++j) xr[ck][ct][j] = col[(size_t)j * Tn];
    }
#pragma unroll
  for (int ck = 0; ck < 2; ++ck) {
    const int kb = 2 * w + ck;
    const float av = a_lds[kb];
#pragma unroll
    for (int ct = 0; ct < 2; ++ct) {
      const int tt = lane + 64 * ct;
      uint4 pk;
      pk.x = pack2_bf16(av * xr[ck][ct][0], av * xr[ck][ct][1]);
      pk.y = pack2_bf16(av * xr[ck][ct][2], av * xr[ck][ct][3]);
      pk.z = pack2_bf16(av * xr[ck][ct][4], av * xr[ck][ct][5]);
      pk.w = pack2_bf16(av * xr[ck][ct][6], av * xr[ck][ct][7]);
      *(uint4*)(buf0 + (size_t)(kb * 128 + tt) * 8) = pk;
    }
  }
  __syncthreads();

  for (int kt = 0; kt < 16; ++kt) {
    unsigned short* cur = (kt & 1) ? buf1 : buf0;
    unsigned short* nxt = (kt & 1) ? buf0 : buf1;
    // ---- prefetch next x tile + next W frags (consumed after MFMA) ----
    if (kt < 15) {
      const int k0n = (kt + 1) * 64;
#pragma unroll
      for (int ck = 0; ck < 2; ++ck)
#pragma unroll
        for (int ct = 0; ct < 2; ++ct) {
          const int kb = 2 * w + ck;
          const float* col = xb + (size_t)(k0n + kb * 8) * Tn + lane + 64 * ct;
#pragma unroll
          for (int j = 0; j < 8; ++j) xr[ck][ct][j] = col[(size_t)j * Tn];
        }
#pragma unroll
      for (int mt = 0; mt < 2; ++mt)
#pragma unroll
        for (int kf = 0; kf < 2; ++kf) {
          const size_t fo = (((size_t)(mtg0 + mt) * 32 + (kt + 1) * 2 + kf) * 64 + lane) * 8;
          wnxt[mt * 4 + kf * 2 + 0] = *(const s16x8*)(whi + fo);
          wnxt[mt * 4 + kf * 2 + 1] = *(const s16x8*)(wlo + fo);
        }
    }
    // ---- MFMA on current tile ----
#pragma unroll
    for (int kf = 0; kf < 2; ++kf) {
      s16x8 bfr[8];
      const int kbr = kf * 4 + quad;
#pragma unroll
      for (int nt = 0; nt < 8; ++nt)
        bfr[nt] = *(const s16x8*)(cur + (size_t)(kbr * 128 + nt * 16 + l15) * 8);
#pragma unroll
      for (int mt = 0; mt < 2; ++mt)
#pragma unroll
        for (int nt = 0; nt < 8; ++nt) {
          acc[mt][nt] = __builtin_amdgcn_mfma_f32_16x16x32_bf16(wcur[mt * 4 + kf * 2 + 0], bfr[nt], acc[mt][nt], 0, 0, 0);
          acc[mt][nt] = __builtin_amdgcn_mfma_f32_16x16x32_bf16(wcur[mt * 4 + kf * 2 + 1], bfr[nt], acc[mt][nt], 0, 0, 0);
        }
    }
    // ---- convert prefetched tile into other buffer; rotate W regs ----
    if (kt < 15) {
#pragma unroll
      for (int ck = 0; ck < 2; ++ck) {
        const int kb = 2 * w + ck;
        const float av = a_lds[(kt + 1) * 8 + kb];
#pragma unroll
        for (int ct = 0; ct < 2; ++ct) {
          const int tt = lane + 64 * ct;
          uint4 pk;
          pk.x = pack2_bf16(av * xr[ck][ct][0], av * xr[ck][ct][1]);
          pk.y = pack2_bf16(av * xr[ck][ct][2], av * xr[ck][ct][3]);
          pk.z = pack2_bf16(av * xr[ck][ct][4], av * xr[ck][ct][5]);
          pk.w = pack2_bf16(av * xr[ck][ct][6], av * xr[ck][ct][7]);
          *(uint4*)(nxt + (size_t)(kb * 128 + tt) * 8) = pk;
        }
      }
#pragma unroll
      for (int i = 0; i < 8; ++i) wcur[i] = wnxt[i];
    }
    __syncthreads();
  }

  // ---- epilogue: acc -> LDS bounce (pitch 136) -> coalesced global f16 ----
#pragma unroll
  for (int mt = 0; mt < 2; ++mt)
#pragma unroll
    for (int nt = 0; nt < 8; ++nt)
#pragma unroll
      for (int r = 0; r < 4; ++r) {
        const int jl = (w * 2 + mt) * 16 + quad * 4 + r;  // 0..127
        lds_out[jl * 136 + nt * 16 + l15] = (_Float16)acc[mt][nt][r];
      }
  __syncthreads();
  {
    const int jr = tid >> 1, half = tid & 1;
    const uint4* lsrc = (const uint4*)(lds_out + jr * 136 + half * 64);
    uint4* gdst = (uint4*)(gx + ((size_t)(b * Mn + p * 128 + jr)) * Tn + half * 64);
#pragma unroll
    for (int i = 0; i < 8; ++i) gdst[i] = lsrc[i];
  }
}

// ---------------------------------------------------------------------------
// K4: LSTM recurrence. 256 blocks (1/batch) x 256 thr.
// R2 restructure: thread d (<128) owns ALL FOUR gate rows {d,128+d,256+d,384+d}.
//  - h-broadcast ds_read_b128 amortizes over 4 rows: 2 active waves x 16 = 32
//    LDS issues/step (was 4 waves x 16 = 64).
//  - nonlinearity is thread-local -> gstep LDS round-trip + its barrier GONE.
//  - h2l double-buffered [2][128] -> no WAR race -> ONE barrier per step.
//  - cost: 256 VGPRs of W_hh rows; __launch_bounds__(256,1) so the allocator
//    targets 1 wave/EU (block is LDS-bound to 1/CU anyway) and doesn't spill.
// Waves 2,3 only help the gxl preload, then just hit the per-step barrier.
// Model: step = max(VALU 512, LDS ~400) + 1 barrier ~= 650-700 cyc
//        vs old max(768 LDS, 256 VALU) + 2 barriers ~= 1000+.
// ---------------------------------------------------------------------------
__global__ __launch_bounds__(256, 1) void k_rec(
    const unsigned short* __restrict__ gx, const uint32_t* __restrict__ whhp,
    const float* __restrict__ b_ih, const float* __restrict__ b_hh,
    float* __restrict__ out) {
  __shared__ unsigned short gxl[512 * 130];  // 133120 B
  __shared__ __align__(16) _Float16 h2l[2 * Hn];  // double buffer

  const int tid = threadIdx.x;
  const int b = blockIdx.x;

  // ---- preload gx[b] (128 KB) into LDS, pitch 130 (all 256 threads) ----
  {
    const uint4* src = (const uint4*)(gx + (size_t)b * Mn * Tn);
#pragma unroll
    for (int it = 0; it < 32; ++it) {
      const int c = it * 256 + tid;     // 16B chunk id, 0..8191
      const int row = c >> 4, off = c & 15;
      uint4 vv = src[c];
      uint32_t* dst = (uint32_t*)((char*)gxl + (size_t)row * 260 + off * 16);
      dst[0] = vv.x; dst[1] = vv.y; dst[2] = vv.z; dst[3] = vv.w;
    }
  }

  const int d = tid;  // valid when tid < 128
  float bi = 0.f, bf = 0.f, bg = 0.f, bo = 0.f;
  h16x2 wi[64], wf[64], wg[64], wo[64];
  if (tid < Hn) {
    bi = b_ih[d] + b_hh[d];
    bf = b_ih[Hn + d] + b_hh[Hn + d];
    bg = b_ih[2 * Hn + d] + b_hh[2 * Hn + d];
    bo = b_ih[3 * Hn + d] + b_hh[3 * Hn + d];
#pragma unroll
    for (int kk = 0; kk < 64; ++kk) {
      union { uint32_t u; h16x2 h; } cv;
      cv.u = whhp[kk * 512 + d];            wi[kk] = cv.h;
      cv.u = whhp[kk * 512 + Hn + d];       wf[kk] = cv.h;
      cv.u = whhp[kk * 512 + 2 * Hn + d];   wg[kk] = cv.h;
      cv.u = whhp[kk * 512 + 3 * Hn + d];   wo[kk] = cv.h;
    }
    h2l[d] = (_Float16)0.f;  // buffer 0 init (t=0 reads buf 0)
  }
  float c_st = 0.f;
  __syncthreads();

  float* outp = out + (size_t)b * Tn * Hn;
  for (int t = 0; t < Tn; ++t) {
    if (tid < Hn) {
      float ai0 = 0.f, ai1 = 0.f, af0 = 0.f, af1 = 0.f;
      float ag0 = 0.f, ag1 = 0.f, ao0 = 0.f, ao1 = 0.f;
      const h16x8* hv = (const h16x8*)(h2l + (size_t)(t & 1) * Hn);
#pragma unroll
      for (int q = 0; q < 16; ++q) {
        union { h16x8 v; h16x2 pr[4]; } u; u.v = hv[q];  // ds_read_b128 broadcast
#if HAVE_FDOT2
        ai0 = __builtin_amdgcn_fdot2(wi[q * 4 + 0], u.pr[0], ai0, false);
        ai1 = __builtin_amdgcn_fdot2(wi[q * 4 + 1], u.pr[1], ai1, false);
        ai0 = __builtin_amdgcn_fdot2(wi[q * 4 + 2], u.pr[2], ai0, false);
        ai1 = __builtin_amdgcn_fdot2(wi[q * 4 + 3], u.pr[3], ai1, false);
        af0 = __builtin_amdgcn_fdot2(wf[q * 4 + 0], u.pr[0], af0, false);
        af1 = __builtin_amdgcn_fdot2(wf[q * 4 + 1], u.pr[1], af1, false);
        af0 = __builtin_amdgcn_fdot2(wf[q * 4 + 2], u.pr[2], af0, false);
        af1 = __builtin_amdgcn_fdot2(wf[q * 4 + 3], u.pr[3], af1, false);
        ag0 = __builtin_amdgcn_fdot2(wg[q * 4 + 0], u.pr[0], ag0, false);
        ag1 = __builtin_amdgcn_fdot2(wg[q * 4 + 1], u.pr[1], ag1, false);
        ag0 = __builtin_amdgcn_fdot2(wg[q * 4 + 2], u.pr[2], ag0, false);
        ag1 = __builtin_amdgcn_fdot2(wg[q * 4 + 3], u.pr[3], ag1, false);
        ao0 = __builtin_amdgcn_fdot2(wo[q * 4 + 0], u.pr[0], ao0, false);
        ao1 = __builtin_amdgcn_fdot2(wo[q * 4 + 1], u.pr[1], ao1, false);
        ao0 = __builtin_amdgcn_fdot2(wo[q * 4 + 2], u.pr[2], ao0, false);
        ao1 = __builtin_amdgcn_fdot2(wo[q * 4 + 3], u.pr[3], ao1, false);
#else
#pragma unroll
        for (int z = 0; z < 4; ++z) {
          ai0 += (float)wi[q * 4 + z].x * (float)u.pr[z].x + (float)wi[q * 4 + z].y * (float)u.pr[z].y;
          af0 += (float)wf[q * 4 + z].x * (float)u.pr[z].x + (float)wf[q * 4 + z].y * (float)u.pr[z].y;
          ag0 += (float)wg[q * 4 + z].x * (float)u.pr[z].x + (float)wg[q * 4 + z].y * (float)u.pr[z].y;
          ao0 += (float)wo[q * 4 + z].x * (float)u.pr[z].x + (float)wo[q * 4 + z].y * (float)u.pr[z].y;
        }
#endif
      }
      const float gi = ai0 + ai1 + bi + (float)(*(const _Float16*)&gxl[d * 130 + t]);
      const float gf = af0 + af1 + bf + (float)(*(const _Float16*)&gxl[(Hn + d) * 130 + t]);
      const float gg = ag0 + ag1 + bg + (float)(*(const _Float16*)&gxl[(2 * Hn + d) * 130 + t]);
      const float go = ao0 + ao1 + bo + (float)(*(const _Float16*)&gxl[(3 * Hn + d) * 130 + t]);
      c_st = sigm(gf) * c_st + sigm(gi) * tanh_fast(gg);
      const float hnew = sigm(go) * tanh_fast(c_st);
      outp[t * Hn + d] = hnew;
      h2l[(size_t)((t + 1) & 1) * Hn + d] = (_Float16)hnew;
    }
    __syncthreads();
  }
}

// ---------------------------------------------------------------------------
extern "C" void kernel_launch(void* const* d_in, const int* in_sizes, int n_in,
                              void* d_out, int out_size, void* d_ws, size_t ws_size,
                              hipStream_t stream) {
  (void)in_sizes; (void)n_in; (void)out_size; (void)ws_size;
  const float* input = (const float*)d_in[0];
  const float* w_attn = (const float*)d_in[1];
  // d_in[2] = b_attn: dead (softmax shift-invariance), as are w_h, w_c.
  const float* W_ih = (const float*)d_in[3];
  const float* W_hh = (const float*)d_in[4];
  const float* b_ih = (const float*)d_in[5];
  const float* b_hh = (const float*)d_in[6];
  float* out = (float*)d_out;

  char* ws = (char*)d_ws;
  float* ex = (float*)ws;                                   // 131072 B
  unsigned short* whi = (unsigned short*)(ws + 131072);      // 1 MB
  unsigned short* wlo = (unsigned short*)(ws + 1179648);     // 1 MB
  uint32_t* whhp = (uint32_t*)(ws + 2228224);                // 131072 B
  unsigned short* gxw = (unsigned short*)(ws + 2359296);     // 33.5 MB

  k_ex<<<8192, 256, 0, stream>>>(input, w_attn, ex);
  k_prep<<<384, 256, 0, stream>>>(W_ih, W_hh, whi, wlo, whhp);
  k_gates<<<1024, 256, 0, stream>>>(input, ex, whi, wlo, gxw);
  k_rec<<<Bn, 256, 0, stream>>>(gxw, whhp, b_ih, b_hh, out);
}

// Round 6
// 359.124 us; speedup vs baseline: 1.2592x; 1.2592x over previous
//
#include <hip/hip_runtime.h>
#include <cstdint>
#include <cstddef>

// Problem dims (B, D, F, T, H) = (256, 128, 8, 128, 128)
#define Bn 256
#define Dn 128
#define Fn 8
#define Tn 128
#define Hn 128
#define Kn 1024   // D*F
#define Mn 512    // 4*H

typedef float f32x4 __attribute__((ext_vector_type(4)));
typedef short s16x8 __attribute__((ext_vector_type(8)));
typedef _Float16 h16x2 __attribute__((ext_vector_type(2)));
typedef _Float16 h16x8 __attribute__((ext_vector_type(8)));

#if defined(__has_builtin)
#if __has_builtin(__builtin_amdgcn_fdot2)
#define HAVE_FDOT2 1
#else
#define HAVE_FDOT2 0
#endif
#if __has_builtin(__builtin_amdgcn_cvt_pkrtz)
#define HAVE_PKRTZ 1
#else
#define HAVE_PKRTZ 0
#endif
#else
#define HAVE_FDOT2 0
#define HAVE_PKRTZ 0
#endif

__device__ __forceinline__ uint32_t pack2_f16(float a, float b) {
#if HAVE_PKRTZ
  // NOTE: builtin returns __fp16 ext_vector(2); union member must match that
  // exact type (R4 compile fix) — bit-reinterpret via the union, no assign
  // across _Float16/__fp16 vector types.
  typedef __fp16 fp16x2_t __attribute__((ext_vector_type(2)));
  union { fp16x2_t v; uint32_t u; } cv;
  cv.v = __builtin_amdgcn_cvt_pkrtz(a, b);
  return cv.u;
#else
  union { h16x2 h; uint32_t u; } cv;
  cv.h.x = (_Float16)a; cv.h.y = (_Float16)b;
  return cv.u;
#endif
}
__device__ __forceinline__ float sigm(float x) { return 1.0f / (1.0f + __expf(-x)); }
__device__ __forceinline__ float tanh_fast(float x) { return 1.0f - 2.0f / (__expf(2.0f * x) + 1.0f); }

// ---------------------------------------------------------------------------
// K1: ex[b,d] = input[b,d,:,:] . w_x   (one wave per (b,d))
// softmax shift-invariance kills the h/c/b_attn term entirely.
// ---------------------------------------------------------------------------
__global__ __launch_bounds__(256) void k_ex(const float* __restrict__ input,
                                            const float* __restrict__ w_attn,
                                            float* __restrict__ ex) {
  __shared__ float wx[Kn];
  const int tid = threadIdx.x;
  ((float4*)wx)[tid] = ((const float4*)(w_attn + 2 * Hn))[tid];
  __syncthreads();
  const int w = tid >> 6, lane = tid & 63;
  const int gid = blockIdx.x * 4 + w;  // b*128 + d
  const float4* xp = (const float4*)(input + (size_t)gid * Kn);
  const float4* wx4 = (const float4*)wx;
  float acc = 0.f;
#pragma unroll
  for (int r = 0; r < 4; ++r) {
    float4 x = xp[lane + r * 64];
    float4 ww = wx4[lane + r * 64];
    acc += x.x * ww.x + x.y * ww.y + x.z * ww.z + x.w * ww.w;
  }
#pragma unroll
  for (int off = 32; off; off >>= 1) acc += __shfl_xor(acc, off);
  if (lane == 0) ex[gid] = acc;
}

// ---------------------------------------------------------------------------
// K2 (merged prep):
//  blocks 0..255 : W_ih -> single f16 MFMA A-frags (R3: was hi/lo bf16 pair;
//                  f16's 11-bit mantissa (2^-11 rel err) beats the bf16 x-hat
//                  error (2^-9) that already bounds accuracy -> one MFMA pass)
//  blocks 256..383: W_hh -> packed f16 pairs transposed (whhp[kk*512+j])
// ---------------------------------------------------------------------------
__global__ __launch_bounds__(256) void k_prep(const float* __restrict__ W_ih,
                                              const float* __restrict__ W_hh,
                                              unsigned short* __restrict__ whf,
                                              uint32_t* __restrict__ whhp) {
  const int bid = blockIdx.x;
  const int tid = threadIdx.x;
  if (bid < 256) {
    const int gid = bid * 256 + tid;  // 65536 groups of 8
    const int lane = gid & 63;
    const int kt = (gid >> 6) & 31;
    const int mt = gid >> 11;
    const int row = mt * 16 + (lane & 15);
    const int col = kt * 32 + (lane >> 4) * 8;
    const float* src = W_ih + row * Kn + col;
    uint4 ph;
    ph.x = pack2_f16(src[0], src[1]);
    ph.y = pack2_f16(src[2], src[3]);
    ph.z = pack2_f16(src[4], src[5]);
    ph.w = pack2_f16(src[6], src[7]);
    ((uint4*)whf)[gid] = ph;
  } else {
    const int g = (bid - 256) * 256 + tid;  // 32768
    const int j = g & 511, kk = g >> 9;
    float2 wv = ((const float2*)(W_hh + (size_t)j * Hn))[kk];
    h16x2 t2; t2.x = (_Float16)wv.x; t2.y = (_Float16)wv.y;
    union { h16x2 h; uint32_t u; } cv; cv.h = t2;
    whhp[kk * 512 + j] = cv.u;
  }
}

// ---------------------------------------------------------------------------
// K3: gates GEMM, f16 single-pass (R3: was bf16 hi/lo = 2x MFMA).
// grid = 1024: b = (bid&7)|((bid>>5)<<3), p = (bid>>3)&3 so the 4 panels of
// one b share an XCD and co-reside -> input[b] fetched ~once per XCD.
// 256 thr. Conflict-free staging layout [kb][t][8k] with lane-contiguous
// ds_write_b128. Register double-buffer for W frags + x prefetch; one
// barrier per K-tile. 16 MFMA_16x16x32_f16 per kt per wave.
// ---------------------------------------------------------------------------
__global__ __launch_bounds__(256, 2) void k_gates(
    const float* __restrict__ input, const float* __restrict__ ex,
    const unsigned short* __restrict__ whf,
    unsigned short* __restrict__ gx) {
  __shared__ __align__(16) unsigned char smem[34816];
  __shared__ float a_lds[Dn];
  __shared__ float sred[8];
  unsigned short* buf0 = (unsigned short*)smem;
  unsigned short* buf1 = buf0 + 8192;
  _Float16* lds_out = (_Float16*)smem;

  const int tid = threadIdx.x;
  const int bid = blockIdx.x;
  const int p = (bid >> 3) & 3;
  const int b = (bid & 7) | ((bid >> 5) << 3);
  const int w = tid >> 6;
  const int lane = tid & 63;
  const int quad = lane >> 4;
  const int l15 = lane & 15;

  // ---- in-block softmax over ex[b,:] -> a_lds ----
  float v = (tid < Dn) ? ex[b * Dn + tid] : -3.4e38f;
  float m = v;
#pragma unroll
  for (int off = 32; off; off >>= 1) m = fmaxf(m, __shfl_xor(m, off));
  if (lane == 0) sred[w] = m;
  __syncthreads();
  m = fmaxf(fmaxf(sred[0], sred[1]), fmaxf(sred[2], sred[3]));
  float e = (tid < Dn) ? __expf(v - m) : 0.f;
  float s = e;
#pragma unroll
  for (int off = 32; off; off >>= 1) s += __shfl_xor(s, off);
  if (lane == 0) sred[4 + w] = s;
  __syncthreads();
  s = sred[4] + sred[5] + sred[6] + sred[7];
  if (tid < Dn) a_lds[tid] = e / s;

  f32x4 acc[2][8];
#pragma unroll
  for (int i = 0; i < 2; ++i)
#pragma unroll
    for (int j = 0; j < 8; ++j) { f32x4 z = {0.f, 0.f, 0.f, 0.f}; acc[i][j] = z; }

  const float* xb = input + (size_t)b * Kn * Tn;
  const int mtg0 = p * 8 + w * 2;

  // W fragment register double-buffer: idx = mt*2 + kf
  h16x8 wcur[4], wnxt[4];
#pragma unroll
  for (int mt = 0; mt < 2; ++mt)
#pragma unroll
    for (int kf = 0; kf < 2; ++kf) {
      const size_t fo = (((size_t)(mtg0 + mt) * 32 + kf) * 64 + lane) * 8;
      wcur[mt * 2 + kf] = *(const h16x8*)(whf + fo);
    }

  __syncthreads();  // a_lds ready

  // ---- stage tile 0 ----
  float xr[2][2][8];
#pragma unroll
  for (int ck = 0; ck < 2; ++ck)
#pragma unroll
    for (int ct = 0; ct < 2; ++ct) {
      const int kb = 2 * w + ck;
      const float* col = xb + (size_t)(kb * 8) * Tn + lane + 64 * ct;
#pragma unroll
      for (int j = 0; j < 8; ++j) xr[ck][ct][j] = col[(size_t)j * Tn];
    }
#pragma unroll
  for (int ck = 0; ck < 2; ++ck) {
    const int kb = 2 * w + ck;
    const float av = a_lds[kb];
#pragma unroll
    for (int ct = 0; ct < 2; ++ct) {
      const int tt = lane + 64 * ct;
      uint4 pk;
      pk.x = pack2_f16(av * xr[ck][ct][0], av * xr[ck][ct][1]);
      pk.y = pack2_f16(av * xr[ck][ct][2], av * xr[ck][ct][3]);
      pk.z = pack2_f16(av * xr[ck][ct][4], av * xr[ck][ct][5]);
      pk.w = pack2_f16(av * xr[ck][ct][6], av * xr[ck][ct][7]);
      *(uint4*)(buf0 + (size_t)(kb * 128 + tt) * 8) = pk;
    }
  }
  __syncthreads();

  for (int kt = 0; kt < 16; ++kt) {
    unsigned short* cur = (kt & 1) ? buf1 : buf0;
    unsigned short* nxt = (kt & 1) ? buf0 : buf1;
    // ---- prefetch next x tile + next W frags (consumed after MFMA) ----
    if (kt < 15) {
      const int k0n = (kt + 1) * 64;
#pragma unroll
      for (int ck = 0; ck < 2; ++ck)
#pragma unroll
        for (int ct = 0; ct < 2; ++ct) {
          const int kb = 2 * w + ck;
          const float* col = xb + (size_t)(k0n + kb * 8) * Tn + lane + 64 * ct;
#pragma unroll
          for (int j = 0; j < 8; ++j) xr[ck][ct][j] = col[(size_t)j * Tn];
        }
#pragma unroll
      for (int mt = 0; mt < 2; ++mt)
#pragma unroll
        for (int kf = 0; kf < 2; ++kf) {
          const size_t fo = (((size_t)(mtg0 + mt) * 32 + (kt + 1) * 2 + kf) * 64 + lane) * 8;
          wnxt[mt * 2 + kf] = *(const h16x8*)(whf + fo);
        }
    }
    // ---- MFMA on current tile ----
#pragma unroll
    for (int kf = 0; kf < 2; ++kf) {
      h16x8 bfr[8];
      const int kbr = kf * 4 + quad;
#pragma unroll
      for (int nt = 0; nt < 8; ++nt)
        bfr[nt] = *(const h16x8*)(cur + (size_t)(kbr * 128 + nt * 16 + l15) * 8);
#pragma unroll
      for (int mt = 0; mt < 2; ++mt)
#pragma unroll
        for (int nt = 0; nt < 8; ++nt) {
          acc[mt][nt] = __builtin_amdgcn_mfma_f32_16x16x32_f16(wcur[mt * 2 + kf], bfr[nt], acc[mt][nt], 0, 0, 0);
        }
    }
    // ---- convert prefetched tile into other buffer; rotate W regs ----
    if (kt < 15) {
#pragma unroll
      for (int ck = 0; ck < 2; ++ck) {
        const int kb = 2 * w + ck;
        const float av = a_lds[(kt + 1) * 8 + kb];
#pragma unroll
        for (int ct = 0; ct < 2; ++ct) {
          const int tt = lane + 64 * ct;
          uint4 pk;
          pk.x = pack2_f16(av * xr[ck][ct][0], av * xr[ck][ct][1]);
          pk.y = pack2_f16(av * xr[ck][ct][2], av * xr[ck][ct][3]);
          pk.z = pack2_f16(av * xr[ck][ct][4], av * xr[ck][ct][5]);
          pk.w = pack2_f16(av * xr[ck][ct][6], av * xr[ck][ct][7]);
          *(uint4*)(nxt + (size_t)(kb * 128 + tt) * 8) = pk;
        }
      }
#pragma unroll
      for (int i = 0; i < 4; ++i) wcur[i] = wnxt[i];
    }
    __syncthreads();
  }

  // ---- epilogue: acc -> LDS bounce (pitch 136) -> coalesced global f16 ----
#pragma unroll
  for (int mt = 0; mt < 2; ++mt)
#pragma unroll
    for (int nt = 0; nt < 8; ++nt)
#pragma unroll
      for (int r = 0; r < 4; ++r) {
        const int jl = (w * 2 + mt) * 16 + quad * 4 + r;  // 0..127
        lds_out[jl * 136 + nt * 16 + l15] = (_Float16)acc[mt][nt][r];
      }
  __syncthreads();
  {
    const int jr = tid >> 1, half = tid & 1;
    const uint4* lsrc = (const uint4*)(lds_out + jr * 136 + half * 64);
    uint4* gdst = (uint4*)(gx + ((size_t)(b * Mn + p * 128 + jr)) * Tn + half * 64);
#pragma unroll
    for (int i = 0; i < 8; ++i) gdst[i] = lsrc[i];
  }
}

// ---------------------------------------------------------------------------
// K4: LSTM recurrence. 256 blocks (1/batch) x 256 thr (2 rows each).
// EXACT 377.6-us-verified structure. The R2 4-gates/thread variant needed
// 256 weight VGPRs, got 140 -> spilled; 4.3 GB of L2 scratch reads made it
// 197 us (VALUBusy 22%, measured). This version's 128 weight VGPRs fit.
// h read as 16x ds_read_b128 broadcast per thread per step; gx LDS pitch 130
// (conflict-free u16 reads). W_hh rows in VGPRs; fdot2.
// ---------------------------------------------------------------------------
__global__ __launch_bounds__(256) void k_rec(
    const unsigned short* __restrict__ gx, const uint32_t* __restrict__ whhp,
    const float* __restrict__ b_ih, const float* __restrict__ b_hh,
    float* __restrict__ out) {
  __shared__ unsigned short gxl[512 * 130];  // 133120 B
  __shared__ float gstep[Mn];
  __shared__ __align__(16) _Float16 h2l[Hn];

  const int tid = threadIdx.x;
  const int b = blockIdx.x;

  // ---- preload gx[b] (128 KB) into LDS, pitch 130 ----
  {
    const uint4* src = (const uint4*)(gx + (size_t)b * Mn * Tn);
#pragma unroll
    for (int it = 0; it < 32; ++it) {
      const int c = it * 256 + tid;     // 16B chunk id, 0..8191
      const int row = c >> 4, off = c & 15;
      uint4 vv = src[c];
      uint32_t* dst = (uint32_t*)((char*)gxl + (size_t)row * 260 + off * 16);
      dst[0] = vv.x; dst[1] = vv.y; dst[2] = vv.z; dst[3] = vv.w;
    }
  }
  const int j0 = tid, j1 = tid + 256;
  const float bs0 = b_ih[j0] + b_hh[j0];
  const float bs1 = b_ih[j1] + b_hh[j1];
  h16x2 wr0[64], wr1[64];
#pragma unroll
  for (int kk = 0; kk < 64; ++kk) {
    union { uint32_t u; h16x2 h; } c0, c1;
    c0.u = whhp[kk * 512 + j0];
    c1.u = whhp[kk * 512 + j1];
    wr0[kk] = c0.h; wr1[kk] = c1.h;
  }
  if (tid < Hn) h2l[tid] = (_Float16)0.f;
  float c_st = 0.f;
  __syncthreads();

  float* outp = out + (size_t)b * Tn * Hn;
  for (int t = 0; t < Tn; ++t) {
    float g0 = bs0 + (float)(*(const _Float16*)&gxl[j0 * 130 + t]);
    float g1 = bs1 + (float)(*(const _Float16*)&gxl[j1 * 130 + t]);
    float a0 = 0.f, a1 = 0.f, a2 = 0.f, a3 = 0.f;
    float d0 = 0.f, d1 = 0.f, d2 = 0.f, d3 = 0.f;
    const h16x8* hv = (const h16x8*)h2l;
#pragma unroll
    for (int q = 0; q < 16; ++q) {
      union { h16x8 v; h16x2 pr[4]; } u; u.v = hv[q];  // ds_read_b128 broadcast
#if HAVE_FDOT2
      a0 = __builtin_amdgcn_fdot2(wr0[q * 4 + 0], u.pr[0], a0, false);
      a1 = __builtin_amdgcn_fdot2(wr0[q * 4 + 1], u.pr[1], a1, false);
      a2 = __builtin_amdgcn_fdot2(wr0[q * 4 + 2], u.pr[2], a2, false);
      a3 = __builtin_amdgcn_fdot2(wr0[q * 4 + 3], u.pr[3], a3, false);
      d0 = __builtin_amdgcn_fdot2(wr1[q * 4 + 0], u.pr[0], d0, false);
      d1 = __builtin_amdgcn_fdot2(wr1[q * 4 + 1], u.pr[1], d1, false);
      d2 = __builtin_amdgcn_fdot2(wr1[q * 4 + 2], u.pr[2], d2, false);
      d3 = __builtin_amdgcn_fdot2(wr1[q * 4 + 3], u.pr[3], d3, false);
#else
#pragma unroll
      for (int z = 0; z < 4; ++z) {
        a0 += (float)wr0[q * 4 + z].x * (float)u.pr[z].x + (float)wr0[q * 4 + z].y * (float)u.pr[z].y;
        d0 += (float)wr1[q * 4 + z].x * (float)u.pr[z].x + (float)wr1[q * 4 + z].y * (float)u.pr[z].y;
      }
#endif
    }
    gstep[j0] = (a0 + a1) + (a2 + a3) + g0;
    gstep[j1] = (d0 + d1) + (d2 + d3) + g1;
    __syncthreads();
    const int d = tid & 127;
    const float gi = gstep[d];
    const float gf = gstep[Hn + d];
    const float gg = gstep[2 * Hn + d];
    const float go = gstep[3 * Hn + d];
    c_st = sigm(gf) * c_st + sigm(gi) * tanh_fast(gg);
    const float hnew = sigm(go) * tanh_fast(c_st);
    if (tid < Hn) {
      outp[t * Hn + d] = hnew;
      h2l[d] = (_Float16)hnew;
    }
    __syncthreads();
  }
}

// ---------------------------------------------------------------------------
extern "C" void kernel_launch(void* const* d_in, const int* in_sizes, int n_in,
                              void* d_out, int out_size, void* d_ws, size_t ws_size,
                              hipStream_t stream) {
  (void)in_sizes; (void)n_in; (void)out_size; (void)ws_size;
  const float* input = (const float*)d_in[0];
  const float* w_attn = (const float*)d_in[1];
  // d_in[2] = b_attn: dead (softmax shift-invariance), as are w_h, w_c.
  const float* W_ih = (const float*)d_in[3];
  const float* W_hh = (const float*)d_in[4];
  const float* b_ih = (const float*)d_in[5];
  const float* b_hh = (const float*)d_in[6];
  float* out = (float*)d_out;

  char* ws = (char*)d_ws;
  float* ex = (float*)ws;                                   // 131072 B
  unsigned short* whf = (unsigned short*)(ws + 131072);      // 1 MB (f16 W_ih frags)
  uint32_t* whhp = (uint32_t*)(ws + 1179648);                // 131072 B
  unsigned short* gxw = (unsigned short*)(ws + 1310720);     // 33.5 MB

  k_ex<<<8192, 256, 0, stream>>>(input, w_attn, ex);
  k_prep<<<384, 256, 0, stream>>>(W_ih, W_hh, whf, whhp);
  k_gates<<<1024, 256, 0, stream>>>(input, ex, whf, gxw);
  k_rec<<<Bn, 256, 0, stream>>>(gxw, whhp, b_ih, b_hh, out);
}

// Round 7
// 357.170 us; speedup vs baseline: 1.2661x; 1.0055x over previous
//
#include <hip/hip_runtime.h>
#include <cstdint>
#include <cstddef>

// Problem dims (B, D, F, T, H) = (256, 128, 8, 128, 128)
#define Bn 256
#define Dn 128
#define Fn 8
#define Tn 128
#define Hn 128
#define Kn 1024   // D*F
#define Mn 512    // 4*H

typedef float f32x4 __attribute__((ext_vector_type(4)));
typedef short s16x8 __attribute__((ext_vector_type(8)));
typedef _Float16 h16x2 __attribute__((ext_vector_type(2)));
typedef _Float16 h16x8 __attribute__((ext_vector_type(8)));

#if defined(__has_builtin)
#if __has_builtin(__builtin_amdgcn_fdot2)
#define HAVE_FDOT2 1
#else
#define HAVE_FDOT2 0
#endif
#if __has_builtin(__builtin_amdgcn_cvt_pkrtz)
#define HAVE_PKRTZ 1
#else
#define HAVE_PKRTZ 0
#endif
#else
#define HAVE_FDOT2 0
#define HAVE_PKRTZ 0
#endif

__device__ __forceinline__ uint32_t pack2_f16(float a, float b) {
#if HAVE_PKRTZ
  // builtin returns __fp16 ext_vector(2); union member must match exactly.
  typedef __fp16 fp16x2_t __attribute__((ext_vector_type(2)));
  union { fp16x2_t v; uint32_t u; } cv;
  cv.v = __builtin_amdgcn_cvt_pkrtz(a, b);
  return cv.u;
#else
  union { h16x2 h; uint32_t u; } cv;
  cv.h.x = (_Float16)a; cv.h.y = (_Float16)b;
  return cv.u;
#endif
}
__device__ __forceinline__ float sigm(float x) { return 1.0f / (1.0f + __expf(-x)); }
__device__ __forceinline__ float tanh_fast(float x) { return 1.0f - 2.0f / (__expf(2.0f * x) + 1.0f); }

// ---------------------------------------------------------------------------
// K1: ex[b,d] = input[b,d,:,:] . w_x   (one wave per (b,d))
// softmax shift-invariance kills the h/c/b_attn term entirely.
// ---------------------------------------------------------------------------
__global__ __launch_bounds__(256) void k_ex(const float* __restrict__ input,
                                            const float* __restrict__ w_attn,
                                            float* __restrict__ ex) {
  __shared__ float wx[Kn];
  const int tid = threadIdx.x;
  ((float4*)wx)[tid] = ((const float4*)(w_attn + 2 * Hn))[tid];
  __syncthreads();
  const int w = tid >> 6, lane = tid & 63;
  const int gid = blockIdx.x * 4 + w;  // b*128 + d
  const float4* xp = (const float4*)(input + (size_t)gid * Kn);
  const float4* wx4 = (const float4*)wx;
  float acc = 0.f;
#pragma unroll
  for (int r = 0; r < 4; ++r) {
    float4 x = xp[lane + r * 64];
    float4 ww = wx4[lane + r * 64];
    acc += x.x * ww.x + x.y * ww.y + x.z * ww.z + x.w * ww.w;
  }
#pragma unroll
  for (int off = 32; off; off >>= 1) acc += __shfl_xor(acc, off);
  if (lane == 0) ex[gid] = acc;
}

// ---------------------------------------------------------------------------
// K2 (merged prep):
//  blocks 0..255 : W_ih -> single f16 MFMA A-frags
//  blocks 256..383: W_hh -> packed f16 pairs transposed (whhp[kk*512+j])
// ---------------------------------------------------------------------------
__global__ __launch_bounds__(256) void k_prep(const float* __restrict__ W_ih,
                                              const float* __restrict__ W_hh,
                                              unsigned short* __restrict__ whf,
                                              uint32_t* __restrict__ whhp) {
  const int bid = blockIdx.x;
  const int tid = threadIdx.x;
  if (bid < 256) {
    const int gid = bid * 256 + tid;  // 65536 groups of 8
    const int lane = gid & 63;
    const int kt = (gid >> 6) & 31;
    const int mt = gid >> 11;
    const int row = mt * 16 + (lane & 15);
    const int col = kt * 32 + (lane >> 4) * 8;
    const float* src = W_ih + row * Kn + col;
    uint4 ph;
    ph.x = pack2_f16(src[0], src[1]);
    ph.y = pack2_f16(src[2], src[3]);
    ph.z = pack2_f16(src[4], src[5]);
    ph.w = pack2_f16(src[6], src[7]);
    ((uint4*)whf)[gid] = ph;
  } else {
    const int g = (bid - 256) * 256 + tid;  // 32768
    const int j = g & 511, kk = g >> 9;
    float2 wv = ((const float2*)(W_hh + (size_t)j * Hn))[kk];
    h16x2 t2; t2.x = (_Float16)wv.x; t2.y = (_Float16)wv.y;
    union { h16x2 h; uint32_t u; } cv; cv.h = t2;
    whhp[kk * 512 + j] = cv.u;
  }
}

// ---------------------------------------------------------------------------
// K3: gates GEMM, f16 single-pass. (Unchanged this round; R6 counters showed
// halving MFMA saved only ~11 us -> staging/latency-bound, not MFMA-bound.
// Next round's top-5 should reveal its counters once k_rec drops below it.)
// ---------------------------------------------------------------------------
__global__ __launch_bounds__(256, 2) void k_gates(
    const float* __restrict__ input, const float* __restrict__ ex,
    const unsigned short* __restrict__ whf,
    unsigned short* __restrict__ gx) {
  __shared__ __align__(16) unsigned char smem[34816];
  __shared__ float a_lds[Dn];
  __shared__ float sred[8];
  unsigned short* buf0 = (unsigned short*)smem;
  unsigned short* buf1 = buf0 + 8192;
  _Float16* lds_out = (_Float16*)smem;

  const int tid = threadIdx.x;
  const int bid = blockIdx.x;
  const int p = (bid >> 3) & 3;
  const int b = (bid & 7) | ((bid >> 5) << 3);
  const int w = tid >> 6;
  const int lane = tid & 63;
  const int quad = lane >> 4;
  const int l15 = lane & 15;

  // ---- in-block softmax over ex[b,:] -> a_lds ----
  float v = (tid < Dn) ? ex[b * Dn + tid] : -3.4e38f;
  float m = v;
#pragma unroll
  for (int off = 32; off; off >>= 1) m = fmaxf(m, __shfl_xor(m, off));
  if (lane == 0) sred[w] = m;
  __syncthreads();
  m = fmaxf(fmaxf(sred[0], sred[1]), fmaxf(sred[2], sred[3]));
  float e = (tid < Dn) ? __expf(v - m) : 0.f;
  float s = e;
#pragma unroll
  for (int off = 32; off; off >>= 1) s += __shfl_xor(s, off);
  if (lane == 0) sred[4 + w] = s;
  __syncthreads();
  s = sred[4] + sred[5] + sred[6] + sred[7];
  if (tid < Dn) a_lds[tid] = e / s;

  f32x4 acc[2][8];
#pragma unroll
  for (int i = 0; i < 2; ++i)
#pragma unroll
    for (int j = 0; j < 8; ++j) { f32x4 z = {0.f, 0.f, 0.f, 0.f}; acc[i][j] = z; }

  const float* xb = input + (size_t)b * Kn * Tn;
  const int mtg0 = p * 8 + w * 2;

  // W fragment register double-buffer: idx = mt*2 + kf
  h16x8 wcur[4], wnxt[4];
#pragma unroll
  for (int mt = 0; mt < 2; ++mt)
#pragma unroll
    for (int kf = 0; kf < 2; ++kf) {
      const size_t fo = (((size_t)(mtg0 + mt) * 32 + kf) * 64 + lane) * 8;
      wcur[mt * 2 + kf] = *(const h16x8*)(whf + fo);
    }

  __syncthreads();  // a_lds ready

  // ---- stage tile 0 ----
  float xr[2][2][8];
#pragma unroll
  for (int ck = 0; ck < 2; ++ck)
#pragma unroll
    for (int ct = 0; ct < 2; ++ct) {
      const int kb = 2 * w + ck;
      const float* col = xb + (size_t)(kb * 8) * Tn + lane + 64 * ct;
#pragma unroll
      for (int j = 0; j < 8; ++j) xr[ck][ct][j] = col[(size_t)j * Tn];
    }
#pragma unroll
  for (int ck = 0; ck < 2; ++ck) {
    const int kb = 2 * w + ck;
    const float av = a_lds[kb];
#pragma unroll
    for (int ct = 0; ct < 2; ++ct) {
      const int tt = lane + 64 * ct;
      uint4 pk;
      pk.x = pack2_f16(av * xr[ck][ct][0], av * xr[ck][ct][1]);
      pk.y = pack2_f16(av * xr[ck][ct][2], av * xr[ck][ct][3]);
      pk.z = pack2_f16(av * xr[ck][ct][4], av * xr[ck][ct][5]);
      pk.w = pack2_f16(av * xr[ck][ct][6], av * xr[ck][ct][7]);
      *(uint4*)(buf0 + (size_t)(kb * 128 + tt) * 8) = pk;
    }
  }
  __syncthreads();

  for (int kt = 0; kt < 16; ++kt) {
    unsigned short* cur = (kt & 1) ? buf1 : buf0;
    unsigned short* nxt = (kt & 1) ? buf0 : buf1;
    // ---- prefetch next x tile + next W frags (consumed after MFMA) ----
    if (kt < 15) {
      const int k0n = (kt + 1) * 64;
#pragma unroll
      for (int ck = 0; ck < 2; ++ck)
#pragma unroll
        for (int ct = 0; ct < 2; ++ct) {
          const int kb = 2 * w + ck;
          const float* col = xb + (size_t)(k0n + kb * 8) * Tn + lane + 64 * ct;
#pragma unroll
          for (int j = 0; j < 8; ++j) xr[ck][ct][j] = col[(size_t)j * Tn];
        }
#pragma unroll
      for (int mt = 0; mt < 2; ++mt)
#pragma unroll
        for (int kf = 0; kf < 2; ++kf) {
          const size_t fo = (((size_t)(mtg0 + mt) * 32 + (kt + 1) * 2 + kf) * 64 + lane) * 8;
          wnxt[mt * 2 + kf] = *(const h16x8*)(whf + fo);
        }
    }
    // ---- MFMA on current tile ----
#pragma unroll
    for (int kf = 0; kf < 2; ++kf) {
      h16x8 bfr[8];
      const int kbr = kf * 4 + quad;
#pragma unroll
      for (int nt = 0; nt < 8; ++nt)
        bfr[nt] = *(const h16x8*)(cur + (size_t)(kbr * 128 + nt * 16 + l15) * 8);
#pragma unroll
      for (int mt = 0; mt < 2; ++mt)
#pragma unroll
        for (int nt = 0; nt < 8; ++nt) {
          acc[mt][nt] = __builtin_amdgcn_mfma_f32_16x16x32_f16(wcur[mt * 2 + kf], bfr[nt], acc[mt][nt], 0, 0, 0);
        }
    }
    // ---- convert prefetched tile into other buffer; rotate W regs ----
    if (kt < 15) {
#pragma unroll
      for (int ck = 0; ck < 2; ++ck) {
        const int kb = 2 * w + ck;
        const float av = a_lds[(kt + 1) * 8 + kb];
#pragma unroll
        for (int ct = 0; ct < 2; ++ct) {
          const int tt = lane + 64 * ct;
          uint4 pk;
          pk.x = pack2_f16(av * xr[ck][ct][0], av * xr[ck][ct][1]);
          pk.y = pack2_f16(av * xr[ck][ct][2], av * xr[ck][ct][3]);
          pk.z = pack2_f16(av * xr[ck][ct][4], av * xr[ck][ct][5]);
          pk.w = pack2_f16(av * xr[ck][ct][6], av * xr[ck][ct][7]);
          *(uint4*)(nxt + (size_t)(kb * 128 + tt) * 8) = pk;
        }
      }
#pragma unroll
      for (int i = 0; i < 4; ++i) wcur[i] = wnxt[i];
    }
    __syncthreads();
  }

  // ---- epilogue: acc -> LDS bounce (pitch 136) -> coalesced global f16 ----
#pragma unroll
  for (int mt = 0; mt < 2; ++mt)
#pragma unroll
    for (int nt = 0; nt < 8; ++nt)
#pragma unroll
      for (int r = 0; r < 4; ++r) {
        const int jl = (w * 2 + mt) * 16 + quad * 4 + r;  // 0..127
        lds_out[jl * 136 + nt * 16 + l15] = (_Float16)acc[mt][nt][r];
      }
  __syncthreads();
  {
    const int jr = tid >> 1, half = tid & 1;
    const uint4* lsrc = (const uint4*)(lds_out + jr * 136 + half * 64);
    uint4* gdst = (uint4*)(gx + ((size_t)(b * Mn + p * 128 + jr)) * Tn + half * 64);
#pragma unroll
    for (int i = 0; i < 8; ++i) gdst[i] = lsrc[i];
  }
}

// ---------------------------------------------------------------------------
// K4: LSTM recurrence. 256 blocks x 256 thr (2 rows/thread).
// R6 restructure: all 4 gates of output d live in ONE wave, split across
// lanes l and l^32. Lane l<32 of wave w: rows {d, d+256} (i,g); lane l>=32:
// rows {d+128, d+384} (f,o); d = w*32 + (l&31). Gate exchange = TWO
// __shfl_xor(.,32) in-register (was: gstep LDS write -> barrier -> read,
// ~120cyc latency + extra barrier). h2l double-buffered -> ONE barrier/step
// (was 2). fdot2 count unchanged (128/thread/step = the per-SIMD floor).
// R3 measured: 2060 cyc/step, VALUBusy 41%, 1 block/CU (grid==CU count, so
// occupancy is structurally capped; critical-path reduction is the lever).
// ---------------------------------------------------------------------------
__global__ __launch_bounds__(256) void k_rec(
    const unsigned short* __restrict__ gx, const uint32_t* __restrict__ whhp,
    const float* __restrict__ b_ih, const float* __restrict__ b_hh,
    float* __restrict__ out) {
  __shared__ unsigned short gxl[512 * 130];  // 133120 B
  __shared__ __align__(16) _Float16 h2l[2][Hn];  // double buffer

  const int tid = threadIdx.x;
  const int b = blockIdx.x;

  // ---- preload gx[b] (128 KB) into LDS, pitch 130 ----
  {
    const uint4* src = (const uint4*)(gx + (size_t)b * Mn * Tn);
#pragma unroll
    for (int it = 0; it < 32; ++it) {
      const int c = it * 256 + tid;     // 16B chunk id, 0..8191
      const int row = c >> 4, off = c & 15;
      uint4 vv = src[c];
      uint32_t* dst = (uint32_t*)((char*)gxl + (size_t)row * 260 + off * 16);
      dst[0] = vv.x; dst[1] = vv.y; dst[2] = vv.z; dst[3] = vv.w;
    }
  }
  const int w = tid >> 6, l = tid & 63;
  const bool lo = (l < 32);
  const int d = w * 32 + (l & 31);        // output dim this lane serves
  const int j0 = d + (lo ? 0 : 128);      // i-row (lo) / f-row (hi)
  const int j1 = j0 + 256;                // g-row (lo) / o-row (hi)
  const float bs0 = b_ih[j0] + b_hh[j0];
  const float bs1 = b_ih[j1] + b_hh[j1];
  h16x2 wr0[64], wr1[64];
#pragma unroll
  for (int kk = 0; kk < 64; ++kk) {
    union { uint32_t u; h16x2 h; } c0, c1;
    c0.u = whhp[kk * 512 + j0];
    c1.u = whhp[kk * 512 + j1];
    wr0[kk] = c0.h; wr1[kk] = c1.h;
  }
  if (tid < Hn) h2l[0][tid] = (_Float16)0.f;
  float c_st = 0.f;
  __syncthreads();

  float* outp = out + (size_t)b * Tn * Hn;
  for (int t = 0; t < Tn; ++t) {
    float g0 = bs0 + (float)(*(const _Float16*)&gxl[j0 * 130 + t]);
    float g1 = bs1 + (float)(*(const _Float16*)&gxl[j1 * 130 + t]);
    float a0 = 0.f, a1 = 0.f, a2 = 0.f, a3 = 0.f;
    float d0 = 0.f, d1 = 0.f, d2 = 0.f, d3 = 0.f;
    const h16x8* hv = (const h16x8*)(&h2l[t & 1][0]);
#pragma unroll
    for (int q = 0; q < 16; ++q) {
      union { h16x8 v; h16x2 pr[4]; } u; u.v = hv[q];  // ds_read_b128 broadcast
#if HAVE_FDOT2
      a0 = __builtin_amdgcn_fdot2(wr0[q * 4 + 0], u.pr[0], a0, false);
      a1 = __builtin_amdgcn_fdot2(wr0[q * 4 + 1], u.pr[1], a1, false);
      a2 = __builtin_amdgcn_fdot2(wr0[q * 4 + 2], u.pr[2], a2, false);
      a3 = __builtin_amdgcn_fdot2(wr0[q * 4 + 3], u.pr[3], a3, false);
      d0 = __builtin_amdgcn_fdot2(wr1[q * 4 + 0], u.pr[0], d0, false);
      d1 = __builtin_amdgcn_fdot2(wr1[q * 4 + 1], u.pr[1], d1, false);
      d2 = __builtin_amdgcn_fdot2(wr1[q * 4 + 2], u.pr[2], d2, false);
      d3 = __builtin_amdgcn_fdot2(wr1[q * 4 + 3], u.pr[3], d3, false);
#else
#pragma unroll
      for (int z = 0; z < 4; ++z) {
        a0 += (float)wr0[q * 4 + z].x * (float)u.pr[z].x + (float)wr0[q * 4 + z].y * (float)u.pr[z].y;
        d0 += (float)wr1[q * 4 + z].x * (float)u.pr[z].x + (float)wr1[q * 4 + z].y * (float)u.pr[z].y;
      }
#endif
    }
    const float a = (a0 + a1) + (a2 + a3) + g0;   // i (lo) / f (hi)
    const float bb = (d0 + d1) + (d2 + d3) + g1;  // g (lo) / o (hi)
    const float aX = __shfl_xor(a, 32);
    const float bX = __shfl_xor(bb, 32);
    const float gi = lo ? a : aX;
    const float gf = lo ? aX : a;
    const float gg = lo ? bb : bX;
    const float go = lo ? bX : bb;
    c_st = sigm(gf) * c_st + sigm(gi) * tanh_fast(gg);
    const float hnew = sigm(go) * tanh_fast(c_st);
    if (lo) {
      outp[t * Hn + d] = hnew;
      h2l[(t + 1) & 1][d] = (_Float16)hnew;
    }
    __syncthreads();  // ONE barrier/step: h2l[nxt] writes -> next-step reads
  }
}

// ---------------------------------------------------------------------------
extern "C" void kernel_launch(void* const* d_in, const int* in_sizes, int n_in,
                              void* d_out, int out_size, void* d_ws, size_t ws_size,
                              hipStream_t stream) {
  (void)in_sizes; (void)n_in; (void)out_size; (void)ws_size;
  const float* input = (const float*)d_in[0];
  const float* w_attn = (const float*)d_in[1];
  // d_in[2] = b_attn: dead (softmax shift-invariance), as are w_h, w_c.
  const float* W_ih = (const float*)d_in[3];
  const float* W_hh = (const float*)d_in[4];
  const float* b_ih = (const float*)d_in[5];
  const float* b_hh = (const float*)d_in[6];
  float* out = (float*)d_out;

  char* ws = (char*)d_ws;
  float* ex = (float*)ws;                                   // 131072 B
  unsigned short* whf = (unsigned short*)(ws + 131072);      // 1 MB (f16 W_ih frags)
  uint32_t* whhp = (uint32_t*)(ws + 1179648);                // 131072 B
  unsigned short* gxw = (unsigned short*)(ws + 1310720);     // 33.5 MB

  k_ex<<<8192, 256, 0, stream>>>(input, w_attn, ex);
  k_prep<<<384, 256, 0, stream>>>(W_ih, W_hh, whf, whhp);
  k_gates<<<1024, 256, 0, stream>>>(input, ex, whf, gxw);
  k_rec<<<Bn, 256, 0, stream>>>(gxw, whhp, b_ih, b_hh, out);
}

// Round 8
// 341.640 us; speedup vs baseline: 1.3236x; 1.0455x over previous
//
#include <hip/hip_runtime.h>
#include <cstdint>
#include <cstddef>

// Problem dims (B, D, F, T, H) = (256, 128, 8, 128, 128)
#define Bn 256
#define Dn 128
#define Fn 8
#define Tn 128
#define Hn 128
#define Kn 1024   // D*F
#define Mn 512    // 4*H

typedef float f32x4 __attribute__((ext_vector_type(4)));
typedef short s16x8 __attribute__((ext_vector_type(8)));
typedef _Float16 h16x2 __attribute__((ext_vector_type(2)));
typedef _Float16 h16x8 __attribute__((ext_vector_type(8)));

#if defined(__has_builtin)
#if __has_builtin(__builtin_amdgcn_cvt_pkrtz)
#define HAVE_PKRTZ 1
#else
#define HAVE_PKRTZ 0
#endif
#else
#define HAVE_PKRTZ 0
#endif

__device__ __forceinline__ uint32_t pack2_f16(float a, float b) {
#if HAVE_PKRTZ
  // builtin returns __fp16 ext_vector(2); union member must match exactly.
  typedef __fp16 fp16x2_t __attribute__((ext_vector_type(2)));
  union { fp16x2_t v; uint32_t u; } cv;
  cv.v = __builtin_amdgcn_cvt_pkrtz(a, b);
  return cv.u;
#else
  union { h16x2 h; uint32_t u; } cv;
  cv.h.x = (_Float16)a; cv.h.y = (_Float16)b;
  return cv.u;
#endif
}
__device__ __forceinline__ float sigm(float x) { return 1.0f / (1.0f + __expf(-x)); }
__device__ __forceinline__ float tanh_fast(float x) { return 1.0f - 2.0f / (__expf(2.0f * x) + 1.0f); }

// ---------------------------------------------------------------------------
// K1: ex[b,d] = input[b,d,:,:] . w_x   (one wave per (b,d))
// softmax shift-invariance kills the h/c/b_attn term entirely.
// ---------------------------------------------------------------------------
__global__ __launch_bounds__(256) void k_ex(const float* __restrict__ input,
                                            const float* __restrict__ w_attn,
                                            float* __restrict__ ex) {
  __shared__ float wx[Kn];
  const int tid = threadIdx.x;
  ((float4*)wx)[tid] = ((const float4*)(w_attn + 2 * Hn))[tid];
  __syncthreads();
  const int w = tid >> 6, lane = tid & 63;
  const int gid = blockIdx.x * 4 + w;  // b*128 + d
  const float4* xp = (const float4*)(input + (size_t)gid * Kn);
  const float4* wx4 = (const float4*)wx;
  float acc = 0.f;
#pragma unroll
  for (int r = 0; r < 4; ++r) {
    float4 x = xp[lane + r * 64];
    float4 ww = wx4[lane + r * 64];
    acc += x.x * ww.x + x.y * ww.y + x.z * ww.z + x.w * ww.w;
  }
#pragma unroll
  for (int off = 32; off; off >>= 1) acc += __shfl_xor(acc, off);
  if (lane == 0) ex[gid] = acc;
}

// ---------------------------------------------------------------------------
// K2 (merged prep):
//  blocks 0..255 : W_ih -> single f16 MFMA A-frags (for k_gates)
//  blocks 256..287: W_hh^T -> f16 MFMA B-frags (for k_rec's MFMA matvec):
//    frag (nt,kf,lane): B[k][n] = W_hh[n][k] with n = nt*16 + (lane&15),
//    k = kf*32 + (lane>>4)*8 + j  (layout identical to the proven k_gates
//    B-frag pattern; 32 nt x 4 kf x 64 lanes x 8 f16 = 128 KiB).
// ---------------------------------------------------------------------------
__global__ __launch_bounds__(256) void k_prep(const float* __restrict__ W_ih,
                                              const float* __restrict__ W_hh,
                                              unsigned short* __restrict__ whf,
                                              unsigned short* __restrict__ whh) {
  const int bid = blockIdx.x;
  const int tid = threadIdx.x;
  if (bid < 256) {
    const int gid = bid * 256 + tid;  // 65536 groups of 8
    const int lane = gid & 63;
    const int kt = (gid >> 6) & 31;
    const int mt = gid >> 11;
    const int row = mt * 16 + (lane & 15);
    const int col = kt * 32 + (lane >> 4) * 8;
    const float* src = W_ih + row * Kn + col;
    uint4 ph;
    ph.x = pack2_f16(src[0], src[1]);
    ph.y = pack2_f16(src[2], src[3]);
    ph.z = pack2_f16(src[4], src[5]);
    ph.w = pack2_f16(src[6], src[7]);
    ((uint4*)whf)[gid] = ph;
  } else {
    const int g = (bid - 256) * 256 + tid;  // 0..8191
    const int l = g & 63;
    const int kf = (g >> 6) & 3;
    const int nt = g >> 8;                  // 0..31
    const int row = nt * 16 + (l & 15);     // gate row n
    const int col = kf * 32 + (l >> 4) * 8; // k
    const float* src = W_hh + (size_t)row * Hn + col;
    uint4 ph;
    ph.x = pack2_f16(src[0], src[1]);
    ph.y = pack2_f16(src[2], src[3]);
    ph.z = pack2_f16(src[4], src[5]);
    ph.w = pack2_f16(src[6], src[7]);
    ((uint4*)whh)[g] = ph;
  }
}

// ---------------------------------------------------------------------------
// K3: gates GEMM, f16 single-pass. (Unchanged; once k_rec drops below it,
// its counters appear in top-5 and guide the next move.)
// ---------------------------------------------------------------------------
__global__ __launch_bounds__(256, 2) void k_gates(
    const float* __restrict__ input, const float* __restrict__ ex,
    const unsigned short* __restrict__ whf,
    unsigned short* __restrict__ gx) {
  __shared__ __align__(16) unsigned char smem[34816];
  __shared__ float a_lds[Dn];
  __shared__ float sred[8];
  unsigned short* buf0 = (unsigned short*)smem;
  unsigned short* buf1 = buf0 + 8192;
  _Float16* lds_out = (_Float16*)smem;

  const int tid = threadIdx.x;
  const int bid = blockIdx.x;
  const int p = (bid >> 3) & 3;
  const int b = (bid & 7) | ((bid >> 5) << 3);
  const int w = tid >> 6;
  const int lane = tid & 63;
  const int quad = lane >> 4;
  const int l15 = lane & 15;

  // ---- in-block softmax over ex[b,:] -> a_lds ----
  float v = (tid < Dn) ? ex[b * Dn + tid] : -3.4e38f;
  float m = v;
#pragma unroll
  for (int off = 32; off; off >>= 1) m = fmaxf(m, __shfl_xor(m, off));
  if (lane == 0) sred[w] = m;
  __syncthreads();
  m = fmaxf(fmaxf(sred[0], sred[1]), fmaxf(sred[2], sred[3]));
  float e = (tid < Dn) ? __expf(v - m) : 0.f;
  float s = e;
#pragma unroll
  for (int off = 32; off; off >>= 1) s += __shfl_xor(s, off);
  if (lane == 0) sred[4 + w] = s;
  __syncthreads();
  s = sred[4] + sred[5] + sred[6] + sred[7];
  if (tid < Dn) a_lds[tid] = e / s;

  f32x4 acc[2][8];
#pragma unroll
  for (int i = 0; i < 2; ++i)
#pragma unroll
    for (int j = 0; j < 8; ++j) { f32x4 z = {0.f, 0.f, 0.f, 0.f}; acc[i][j] = z; }

  const float* xb = input + (size_t)b * Kn * Tn;
  const int mtg0 = p * 8 + w * 2;

  // W fragment register double-buffer: idx = mt*2 + kf
  h16x8 wcur[4], wnxt[4];
#pragma unroll
  for (int mt = 0; mt < 2; ++mt)
#pragma unroll
    for (int kf = 0; kf < 2; ++kf) {
      const size_t fo = (((size_t)(mtg0 + mt) * 32 + kf) * 64 + lane) * 8;
      wcur[mt * 2 + kf] = *(const h16x8*)(whf + fo);
    }

  __syncthreads();  // a_lds ready

  // ---- stage tile 0 ----
  float xr[2][2][8];
#pragma unroll
  for (int ck = 0; ck < 2; ++ck)
#pragma unroll
    for (int ct = 0; ct < 2; ++ct) {
      const int kb = 2 * w + ck;
      const float* col = xb + (size_t)(kb * 8) * Tn + lane + 64 * ct;
#pragma unroll
      for (int j = 0; j < 8; ++j) xr[ck][ct][j] = col[(size_t)j * Tn];
    }
#pragma unroll
  for (int ck = 0; ck < 2; ++ck) {
    const int kb = 2 * w + ck;
    const float av = a_lds[kb];
#pragma unroll
    for (int ct = 0; ct < 2; ++ct) {
      const int tt = lane + 64 * ct;
      uint4 pk;
      pk.x = pack2_f16(av * xr[ck][ct][0], av * xr[ck][ct][1]);
      pk.y = pack2_f16(av * xr[ck][ct][2], av * xr[ck][ct][3]);
      pk.z = pack2_f16(av * xr[ck][ct][4], av * xr[ck][ct][5]);
      pk.w = pack2_f16(av * xr[ck][ct][6], av * xr[ck][ct][7]);
      *(uint4*)(buf0 + (size_t)(kb * 128 + tt) * 8) = pk;
    }
  }
  __syncthreads();

  for (int kt = 0; kt < 16; ++kt) {
    unsigned short* cur = (kt & 1) ? buf1 : buf0;
    unsigned short* nxt = (kt & 1) ? buf0 : buf1;
    // ---- prefetch next x tile + next W frags (consumed after MFMA) ----
    if (kt < 15) {
      const int k0n = (kt + 1) * 64;
#pragma unroll
      for (int ck = 0; ck < 2; ++ck)
#pragma unroll
        for (int ct = 0; ct < 2; ++ct) {
          const int kb = 2 * w + ck;
          const float* col = xb + (size_t)(k0n + kb * 8) * Tn + lane + 64 * ct;
#pragma unroll
          for (int j = 0; j < 8; ++j) xr[ck][ct][j] = col[(size_t)j * Tn];
        }
#pragma unroll
      for (int mt = 0; mt < 2; ++mt)
#pragma unroll
        for (int kf = 0; kf < 2; ++kf) {
          const size_t fo = (((size_t)(mtg0 + mt) * 32 + (kt + 1) * 2 + kf) * 64 + lane) * 8;
          wnxt[mt * 2 + kf] = *(const h16x8*)(whf + fo);
        }
    }
    // ---- MFMA on current tile ----
#pragma unroll
    for (int kf = 0; kf < 2; ++kf) {
      h16x8 bfr[8];
      const int kbr = kf * 4 + quad;
#pragma unroll
      for (int nt = 0; nt < 8; ++nt)
        bfr[nt] = *(const h16x8*)(cur + (size_t)(kbr * 128 + nt * 16 + l15) * 8);
#pragma unroll
      for (int mt = 0; mt < 2; ++mt)
#pragma unroll
        for (int nt = 0; nt < 8; ++nt) {
          acc[mt][nt] = __builtin_amdgcn_mfma_f32_16x16x32_f16(wcur[mt * 2 + kf], bfr[nt], acc[mt][nt], 0, 0, 0);
        }
    }
    // ---- convert prefetched tile into other buffer; rotate W regs ----
    if (kt < 15) {
#pragma unroll
      for (int ck = 0; ck < 2; ++ck) {
        const int kb = 2 * w + ck;
        const float av = a_lds[(kt + 1) * 8 + kb];
#pragma unroll
        for (int ct = 0; ct < 2; ++ct) {
          const int tt = lane + 64 * ct;
          uint4 pk;
          pk.x = pack2_f16(av * xr[ck][ct][0], av * xr[ck][ct][1]);
          pk.y = pack2_f16(av * xr[ck][ct][2], av * xr[ck][ct][3]);
          pk.z = pack2_f16(av * xr[ck][ct][4], av * xr[ck][ct][5]);
          pk.w = pack2_f16(av * xr[ck][ct][6], av * xr[ck][ct][7]);
          *(uint4*)(nxt + (size_t)(kb * 128 + tt) * 8) = pk;
        }
      }
#pragma unroll
      for (int i = 0; i < 4; ++i) wcur[i] = wnxt[i];
    }
    __syncthreads();
  }

  // ---- epilogue: acc -> LDS bounce (pitch 136) -> coalesced global f16 ----
#pragma unroll
  for (int mt = 0; mt < 2; ++mt)
#pragma unroll
    for (int nt = 0; nt < 8; ++nt)
#pragma unroll
      for (int r = 0; r < 4; ++r) {
        const int jl = (w * 2 + mt) * 16 + quad * 4 + r;  // 0..127
        lds_out[jl * 136 + nt * 16 + l15] = (_Float16)acc[mt][nt][r];
      }
  __syncthreads();
  {
    const int jr = tid >> 1, half = tid & 1;
    const uint4* lsrc = (const uint4*)(lds_out + jr * 136 + half * 64);
    uint4* gdst = (uint4*)(gx + ((size_t)(b * Mn + p * 128 + jr)) * Tn + half * 64);
#pragma unroll
    for (int i = 0; i < 8; ++i) gdst[i] = lsrc[i];
  }
}

// ---------------------------------------------------------------------------
// K4: LSTM recurrence via MFMA. 256 blocks x 256 thr.
// R7: the W_hh.h matvec moves off the VALU onto the idle MFMA pipe.
// Evidence: R6 counters (VALUBusy 49% at 2100 cyc/step, MfmaUtil 0.0) imply
// v_dot2_f32_f16 issues at ~8 cyc -> k_rec was VALU-issue-bound on fdot2.
// Scheme: A-operand = h broadcast to ALL lanes (every A row = h), so every
// C row = gates and each lane finds gate[col=lane&15] IN-LANE (acc reg
// selected by 6 static-index cndmasks; no cross-lane extraction). B = W_hh^T
// frags preloaded once (32 x h16x8 = 128 VGPRs, same budget as old wr0/wr1).
// Per thread per step: 4 ds_read_b128 (was 16) + 32 MFMA + ~50 VALU.
// Wave w owns d in [32w,32w+32): n-tiles {2w,2w+1, 8+2w,9+2w, 16+..., 24+...}
// -> lo lane l: (i_d,g_d), hi lane: (f_d,o_d), d=w*32+(l&31) == R6 mapping;
// gate exchange/nonlinearity/h-writeback code reused verbatim from R6.
// ---------------------------------------------------------------------------
__global__ __launch_bounds__(256, 1) void k_rec(
    const unsigned short* __restrict__ gx, const unsigned short* __restrict__ whh,
    const float* __restrict__ b_ih, const float* __restrict__ b_hh,
    float* __restrict__ out) {
  __shared__ unsigned short gxl[512 * 130];  // 133120 B
  __shared__ __align__(16) _Float16 h2l[2][Hn];  // double buffer

  const int tid = threadIdx.x;
  const int b = blockIdx.x;

  // ---- preload gx[b] (128 KB) into LDS, pitch 130 ----
  {
    const uint4* src = (const uint4*)(gx + (size_t)b * Mn * Tn);
#pragma unroll
    for (int it = 0; it < 32; ++it) {
      const int c = it * 256 + tid;     // 16B chunk id, 0..8191
      const int row = c >> 4, off = c & 15;
      uint4 vv = src[c];
      uint32_t* dst = (uint32_t*)((char*)gxl + (size_t)row * 260 + off * 16);
      dst[0] = vv.x; dst[1] = vv.y; dst[2] = vv.z; dst[3] = vv.w;
    }
  }
  const int w = tid >> 6, l = tid & 63;
  const bool lo = (l < 32);
  const int d = w * 32 + (l & 31);        // output dim this lane serves
  const int j0 = d + (lo ? 0 : 128);      // i-row (lo) / f-row (hi)
  const int j1 = j0 + 256;                // g-row (lo) / o-row (hi)
  const float bs0 = b_ih[j0] + b_hh[j0];
  const float bs1 = b_ih[j1] + b_hh[j1];

  // ---- preload W_hh^T B-frags: 8 n-tiles x 4 k-frags (128 VGPRs) ----
  h16x8 wf[8][4];
#pragma unroll
  for (int ntl = 0; ntl < 8; ++ntl) {
    const int nt = (ntl >> 1) * 8 + 2 * w + (ntl & 1);
#pragma unroll
    for (int kf = 0; kf < 4; ++kf) {
      const size_t fo = (((size_t)nt * 4 + kf) * 64 + l) * 8;
      wf[ntl][kf] = *(const h16x8*)(whh + fo);
    }
  }
  if (tid < Hn) h2l[0][tid] = (_Float16)0.f;
  float c_st = 0.f;
  __syncthreads();

  float* outp = out + (size_t)b * Tn * Hn;
  const int aoff = (l >> 4) * 8;  // k-slice this lane supplies to A-frags
  for (int t = 0; t < Tn; ++t) {
    const float g0 = bs0 + (float)(*(const _Float16*)&gxl[j0 * 130 + t]);
    const float g1 = bs1 + (float)(*(const _Float16*)&gxl[j1 * 130 + t]);
    // A-frags: h broadcast (16-lane-group b128 reads, conflict-free)
    const _Float16* hb = &h2l[t & 1][0];
    h16x8 af0 = *(const h16x8*)(hb + 0 * 32 + aoff);
    h16x8 af1 = *(const h16x8*)(hb + 1 * 32 + aoff);
    h16x8 af2 = *(const h16x8*)(hb + 2 * 32 + aoff);
    h16x8 af3 = *(const h16x8*)(hb + 3 * 32 + aoff);
    f32x4 acc[8];
#pragma unroll
    for (int ntl = 0; ntl < 8; ++ntl) {
      f32x4 z = {0.f, 0.f, 0.f, 0.f};
      z = __builtin_amdgcn_mfma_f32_16x16x32_f16(af0, wf[ntl][0], z, 0, 0, 0);
      z = __builtin_amdgcn_mfma_f32_16x16x32_f16(af1, wf[ntl][1], z, 0, 0, 0);
      z = __builtin_amdgcn_mfma_f32_16x16x32_f16(af2, wf[ntl][2], z, 0, 0, 0);
      z = __builtin_amdgcn_mfma_f32_16x16x32_f16(af3, wf[ntl][3], z, 0, 0, 0);
      acc[ntl] = z;
    }
    // in-lane gate pick: every C row = gates, lane's col = l&15 (static idx)
    const float va = (l < 16) ? acc[0][0] : (l < 32) ? acc[1][0]
                   : (l < 48) ? acc[2][0] : acc[3][0];   // i (lo) / f (hi)
    const float vb = (l < 16) ? acc[4][0] : (l < 32) ? acc[5][0]
                   : (l < 48) ? acc[6][0] : acc[7][0];   // g (lo) / o (hi)
    const float a = va + g0;
    const float bb = vb + g1;
    const float aX = __shfl_xor(a, 32);
    const float bX = __shfl_xor(bb, 32);
    const float gi = lo ? a : aX;
    const float gf = lo ? aX : a;
    const float gg = lo ? bb : bX;
    const float go = lo ? bX : bb;
    c_st = sigm(gf) * c_st + sigm(gi) * tanh_fast(gg);
    const float hnew = sigm(go) * tanh_fast(c_st);
    if (lo) {
      outp[t * Hn + d] = hnew;
      h2l[(t + 1) & 1][d] = (_Float16)hnew;
    }
    __syncthreads();  // h2l[nxt] writes -> next-step A-frag reads
  }
}

// ---------------------------------------------------------------------------
extern "C" void kernel_launch(void* const* d_in, const int* in_sizes, int n_in,
                              void* d_out, int out_size, void* d_ws, size_t ws_size,
                              hipStream_t stream) {
  (void)in_sizes; (void)n_in; (void)out_size; (void)ws_size;
  const float* input = (const float*)d_in[0];
  const float* w_attn = (const float*)d_in[1];
  // d_in[2] = b_attn: dead (softmax shift-invariance), as are w_h, w_c.
  const float* W_ih = (const float*)d_in[3];
  const float* W_hh = (const float*)d_in[4];
  const float* b_ih = (const float*)d_in[5];
  const float* b_hh = (const float*)d_in[6];
  float* out = (float*)d_out;

  char* ws = (char*)d_ws;
  float* ex = (float*)ws;                                   // 131072 B
  unsigned short* whf = (unsigned short*)(ws + 131072);      // 1 MB (f16 W_ih frags)
  unsigned short* whh = (unsigned short*)(ws + 1179648);     // 131072 B (W_hh^T B-frags)
  unsigned short* gxw = (unsigned short*)(ws + 1310720);     // 33.5 MB

  k_ex<<<8192, 256, 0, stream>>>(input, w_attn, ex);
  k_prep<<<288, 256, 0, stream>>>(W_ih, W_hh, whf, whh);
  k_gates<<<1024, 256, 0, stream>>>(input, ex, whf, gxw);
  k_rec<<<Bn, 256, 0, stream>>>(gxw, whh, b_ih, b_hh, out);
}